// Round 2
// baseline (485.086 us; speedup 1.0000x reference)
//
#include <hip/hip_runtime.h>
#include <math.h>

// (B,H,L,D) = (8,8,2048,512).  rows = B*H*L = 131072, FFT length 512.
// Identity:  Re(ifft(W . fft(x))) == ifft(Wp . fft(x)),  Wp[k] = (W[k]+conj(W[(N-k)%N]))/2
// Wp Hermitian => real result for real x; map is C-linear, so two real rows sharing a
// weight row pack as z = x1 + i*x2:  ifft(Wp.fft(z)) = out1 + i*out2 exactly.
// Inverse via forward FFT:  ifft(G) = conj(fft(conj(G)))/N  (the /N is folded into Wp).
//
// This version: persistent blocks, cross-tile software pipeline.
//  - each block owns 8 hl rows (hl = blockIdx.x + 2048*it)
//  - next tile's x rows prefetched into LDS via global_load_lds DURING current FFTs
//  - counted s_waitcnt vmcnt(16) at loop head: prev tile's 16 stores stay in flight
//  - wk half of gate row loaded to regs at tile start (latency covered by FFT1);
//    wnk half loaded at gate time (L1 hit: same 4KB row already touched)
//  - no __syncthreads anywhere -> compiler never force-drains vmcnt

#define HL    16384
#define NBLK  2048
#define ITERS (HL / NBLK)     // 8

__device__ __forceinline__ float2 cadd(float2 a, float2 b){ return make_float2(a.x+b.x, a.y+b.y); }
__device__ __forceinline__ float2 csub(float2 a, float2 b){ return make_float2(a.x-b.x, a.y-b.y); }
__device__ __forceinline__ float2 cmul(float2 a, float2 b){ return make_float2(a.x*b.x - a.y*b.y, a.x*b.y + a.y*b.x); }

// exp(-2*pi*i*f), f in revolutions. v_sin_f32/v_cos_f32 take revolutions -> 1 inst each.
__device__ __forceinline__ float2 twiddle(float f) {
    return make_float2(__builtin_amdgcn_cosf(f), -__builtin_amdgcn_sinf(f));
}

// w[k] = exp(-2*pi*i*f*k), k=1..7, log-depth power build
__device__ __forceinline__ void twiddle_pows(float f, float2 w[8]) {
    w[1] = twiddle(f);
    w[2] = cmul(w[1], w[1]);
    w[3] = cmul(w[1], w[2]);
    w[4] = cmul(w[2], w[2]);
    w[5] = cmul(w[1], w[4]);
    w[6] = cmul(w[2], w[4]);
    w[7] = cmul(w[3], w[4]);
}

// Wave-level LDS ordering: scratch is private to the wave, so no block barrier needed.
__device__ __forceinline__ void wave_lds_fence() {
    asm volatile("s_waitcnt lgkmcnt(0)" ::: "memory");
    __builtin_amdgcn_wave_barrier();
}

// 8-point DFT, natural order, forward sign.
__device__ __forceinline__ void fft8(float2 x[8]) {
    const float c = 0.70710678118654752f;
    float2 u0 = cadd(x[0], x[4]);
    float2 u1 = cadd(x[1], x[5]);
    float2 u2 = cadd(x[2], x[6]);
    float2 u3 = cadd(x[3], x[7]);
    float2 v0 = csub(x[0], x[4]);
    float2 t1 = csub(x[1], x[5]);
    float2 t2 = csub(x[2], x[6]);
    float2 t3 = csub(x[3], x[7]);
    float2 v1 = make_float2(c*(t1.x + t1.y), c*(t1.y - t1.x));   // * W8^1
    float2 v2 = make_float2(t2.y, -t2.x);                        // * W8^2
    float2 v3 = make_float2(c*(t3.y - t3.x), -c*(t3.x + t3.y));  // * W8^3
    float2 p0 = cadd(u0, u2), p1 = cadd(u1, u3);
    float2 q0 = csub(u0, u2), q1t = csub(u1, u3);
    float2 q1 = make_float2(q1t.y, -q1t.x);
    x[0] = cadd(p0, p1);
    x[4] = csub(p0, p1);
    x[2] = cadd(q0, q1);
    x[6] = csub(q0, q1);
    float2 r0 = cadd(v0, v2), r1 = cadd(v1, v3);
    float2 s0 = csub(v0, v2), s1t = csub(v1, v3);
    float2 s1 = make_float2(s1t.y, -s1t.x);
    x[1] = cadd(r0, r1);
    x[5] = csub(r0, r1);
    x[3] = cadd(s0, s1);
    x[7] = csub(s0, s1);
}

// 512-pt forward FFT, one wave, 8 complex per lane, AoS float2 scratch (8*72 per wave).
// Input: lane with role r holds z[64*j + r] in v[j].
// Output: lane holds Z[ds(lane) + 64*j] in v[j], ds(r) = ((r&7)<<3)|(r>>3).
// All LDS patterns spread exactly 4 lanes/bank (b64) = bandwidth minimum.
__device__ __forceinline__ void fft512(float2 v[8], int role, int lane, float2* sc)
{
    // ---- stage 1: radix-8 over stride 64, twiddle W512^{role*k1} ----
    fft8(v);
    {
        float2 w[8];
        twiddle_pows((float)role * (1.0f/512.0f), w);
        #pragma unroll
        for (int k = 1; k < 8; ++k) v[k] = cmul(v[k], w[k]);
    }
    wave_lds_fence();                // WAR: prior reads of scratch drained
    #pragma unroll
    for (int k1 = 0; k1 < 8; ++k1) sc[k1*72 + role] = v[k1];
    wave_lds_fence();
    // ---- stage 2: 8 independent 64-pt FFTs; radix-8 over stride 8 ----
    const int k1 = lane >> 3, m2 = lane & 7;
    float2 u[8];
    #pragma unroll
    for (int m1 = 0; m1 < 8; ++m1) u[m1] = sc[k1*72 + 8*m1 + m2];
    fft8(u);
    {
        float2 w[8];
        twiddle_pows((float)m2 * (1.0f/64.0f), w);
        #pragma unroll
        for (int j = 1; j < 8; ++j) u[j] = cmul(u[j], w[j]);
    }
    wave_lds_fence();                // WAR: stage-2 reads done before overwrite
    #pragma unroll
    for (int j1 = 0; j1 < 8; ++j1) sc[k1*72 + 9*j1 + m2] = u[j1];
    wave_lds_fence();
    // ---- stage 3: radix-8 over stride 1, no twiddle ----
    const int j1 = lane & 7;
    #pragma unroll
    for (int m = 0; m < 8; ++m) v[m] = sc[k1*72 + 9*j1 + m];
    fft8(v);                         // v[j2] = X[k1 + 8*j1 + 64*j2]
}

// address-space typedefs for global_load_lds
using gu32 = __attribute__((address_space(1))) const unsigned int;
using lu32 = __attribute__((address_space(3))) unsigned int;

__global__ __launch_bounds__(256) void sgn_fft_pipe(
    const float* __restrict__ x,
    const float* __restrict__ cw,    // (H,L,512,2)
    float* __restrict__ out)
{
    __shared__ __align__(16) float2 sc[4][8*72];   // per-wave FFT scratch
    __shared__ __align__(16) float  inb[4][2][512];// per-wave input double-use buffer

    const int tid  = threadIdx.x;
    const int wid  = tid >> 6;       // wave id in [0,4): packed pair (batches wid, wid+4)
    const int lane = tid & 63;
    const int dsl  = ((lane & 7) << 3) | (lane >> 3);

    const float2* __restrict__ cw2 = (const float2*)cw;
    float2* scw = &sc[wid][0];

    // ---- prologue: prefetch tile 0 into LDS ----
    {
        const int hl = blockIdx.x;
        const int r1 = (wid       * HL + hl) * 512;
        const int r2 = ((wid + 4) * HL + hl) * 512;
        #pragma unroll
        for (int c = 0; c < 2; ++c) {
            __builtin_amdgcn_global_load_lds((gu32*)(x + r1 + c*256 + lane*4),
                                             (lu32*)(&inb[wid][0][c*256]), 16, 0, 0);
            __builtin_amdgcn_global_load_lds((gu32*)(x + r2 + c*256 + lane*4),
                                             (lu32*)(&inb[wid][1][c*256]), 16, 0, 0);
        }
    }
    asm volatile("s_waitcnt vmcnt(0)" ::: "memory");

    #pragma unroll 1
    for (int it = 0; it < ITERS; ++it) {
        const int hl = blockIdx.x + NBLK * it;
        const int r1 = (wid       * HL + hl) * 512;
        const int r2 = ((wid + 4) * HL + hl) * 512;
        const int wrow = hl * 512;

        // everything older than the previous tile's 16 stores has retired
        // (incl. this tile's 4 global_load_lds). Stores stay in flight.
        asm volatile("s_waitcnt vmcnt(16)" ::: "memory");

        // unpack: z = x1 + i*x2, lane r holds z[64j + r]
        float2 v[8];
        #pragma unroll
        for (int j = 0; j < 8; ++j) {
            v[j].x = inb[wid][0][64*j + lane];
            v[j].y = inb[wid][1][64*j + lane];
        }
        wave_lds_fence();            // reads retired before DMA may overwrite inb

        // ---- issue next tile's prefetch; lands during the two FFTs ----
        if (it + 1 < ITERS) {
            const int hln = hl + NBLK;
            const int r1n = (wid       * HL + hln) * 512;
            const int r2n = ((wid + 4) * HL + hln) * 512;
            #pragma unroll
            for (int c = 0; c < 2; ++c) {
                __builtin_amdgcn_global_load_lds((gu32*)(x + r1n + c*256 + lane*4),
                                                 (lu32*)(&inb[wid][0][c*256]), 16, 0, 0);
                __builtin_amdgcn_global_load_lds((gu32*)(x + r2n + c*256 + lane*4),
                                                 (lu32*)(&inb[wid][1][c*256]), 16, 0, 0);
            }
        }

        // ---- issue wk loads now; latency covered by FFT1 ----
        float2 wk[8];
        #pragma unroll
        for (int j2 = 0; j2 < 8; ++j2) wk[j2] = cw2[wrow + dsl + 64*j2];

        fft512(v, lane, lane, scw);

        // gate: G = Wp * Z (Wp pre-scaled by 1/512), then conj for inverse-via-forward
        const float hs = 0.5f / 512.0f;
        #pragma unroll
        for (int j2 = 0; j2 < 8; ++j2) {
            const int k  = dsl + 64*j2;
            const int nk = (512 - k) & 511;
            const float2 wnk = cw2[wrow + nk];    // L1 hit: row touched by wk loads
            const float2 wp  = make_float2(hs*(wk[j2].x + wnk.x), hs*(wk[j2].y - wnk.y));
            const float2 g   = cmul(wp, v[j2]);
            v[j2] = make_float2(g.x, -g.y);
        }

        fft512(v, dsl, lane, scw);

        // Y = fft(conj(G)); out1 = Re(Y), out2 = -Im(Y) at k = ds(lane)+64*j2
        #pragma unroll
        for (int j2 = 0; j2 < 8; ++j2) {
            const int k = dsl + 64*j2;
            out[r1 + k] =  v[j2].x;
            out[r2 + k] = -v[j2].y;
        }
    }
}

extern "C" void kernel_launch(void* const* d_in, const int* in_sizes, int n_in,
                              void* d_out, int out_size, void* d_ws, size_t ws_size,
                              hipStream_t stream) {
    const float* x  = (const float*)d_in[0];   // (B,H,L,D) fp32
    // d_in[1] = mask, unused
    const float* cw = (const float*)d_in[2];   // (H,L,D,2) fp32
    float* out = (float*)d_out;

    sgn_fft_pipe<<<dim3(NBLK), dim3(256), 0, stream>>>(x, cw, out);
}